// Round 9
// baseline (13024.864 us; speedup 1.0000x reference)
//
#include <hip/hip_runtime.h>
#include <hip/hip_bf16.h>

#define B_  64
#define T_  12
#define N_  325
#define DIN 2
#define H_  128
#define BN  (B_*N_)    // 20800
#define DPITCH 384     // padded node pitch (k-extent) for transposed/support buffers
#define AROWS 384      // padded m-rows per support matrix
#define CPAD0 192
#define CPAD1 256

typedef __hip_bfloat16 bf16;
typedef unsigned short u16;
typedef __attribute__((ext_vector_type(8))) short short8;
typedef __attribute__((ext_vector_type(4))) float f32x4;

__device__ __forceinline__ float b2f(bf16 v){ return __bfloat162float(v); }
__device__ __forceinline__ u16 f2b(float f){
    __hip_bfloat16 h = __float2bfloat16(f);
    return *reinterpret_cast<u16*>(&h);
}

// async global->LDS, 16B per lane; dest = base + lane*16 (wave-uniform base)
__device__ __forceinline__ void gl_lds16(const u16* g, u16* l){
    __builtin_amdgcn_global_load_lds(
        (const __attribute__((address_space(1))) unsigned int*)g,
        (__attribute__((address_space(3))) unsigned int*)l, 16, 0, 0);
}

// ---------------------------------------------------------------------------
// Dtype sniffer + one-shot fp32 conversion of all float inputs
// ---------------------------------------------------------------------------
__global__ void sniff(const void* __restrict__ sup, int* __restrict__ flag){
    if (threadIdx.x == 0 && blockIdx.x == 0){
        float sb = 0.f, sf = 0.f;
        for (int n = 0; n < N_; ++n){
            sb += b2f(((const bf16*)sup)[n]);
            sf += ((const float*)sup)[n];
        }
        float db = fabsf(sb - 1.f), df = fabsf(sf - 1.f);
        *flag = (db < df) ? 1 : 0;
    }
}

struct CvtArgs {
    const void* src[20];
    float*      dst[20];
    int         n[20];
};

__global__ void cvt_all(CvtArgs a, const int* __restrict__ flag){
    int ii = blockIdx.y;
    int i  = blockIdx.x*256 + threadIdx.x;
    int n  = a.n[ii];
    if (i >= n) return;
    if (*flag) a.dst[ii][i] = b2f(((const bf16*)a.src[ii])[i]);
    else       a.dst[ii][i] = ((const float*)a.src[ii])[i];
}

// ---------------------------------------------------------------------------
// msq[0]=S0, msq[1]=S0@S0, msq[2]=S1, msq[3]=S1@S1   (fp32)
// ---------------------------------------------------------------------------
__global__ void support_prep(const float* __restrict__ sup, float* __restrict__ msq){
    int s = blockIdx.z;
    int m = blockIdx.y*16 + threadIdx.y;
    int n = blockIdx.x*16 + threadIdx.x;
    __shared__ float As[16][17], Bs[16][17];
    const float* S = sup + (size_t)s*N_*N_;
    float acc = 0.f;
    for (int j0 = 0; j0 < N_; j0 += 16){
        As[threadIdx.y][threadIdx.x] = (m < N_ && j0+threadIdx.x < N_) ? S[m*N_ + j0+threadIdx.x] : 0.f;
        Bs[threadIdx.y][threadIdx.x] = (j0+threadIdx.y < N_ && n < N_) ? S[(j0+threadIdx.y)*N_ + n] : 0.f;
        __syncthreads();
        #pragma unroll
        for (int jj=0; jj<16; ++jj) acc += As[threadIdx.y][jj]*Bs[jj][threadIdx.x];
        __syncthreads();
    }
    if (m < N_ && n < N_){
        msq[(size_t)(2*s  )*N_*N_ + m*N_ + n] = S[m*N_ + n];
        msq[(size_t)(2*s+1)*N_*N_ + m*N_ + n] = acc;
    }
}

// asq[k][m<384][col<384] = bf16(msq[k][m][col]) zero-padded in rows AND cols
__global__ void asq_prep(const float* __restrict__ msq, u16* __restrict__ asq){
    int idx = blockIdx.x*256 + threadIdx.x;
    int total = 4*AROWS*DPITCH;
    if (idx >= total) return;
    int col = idx % DPITCH;
    int rm  = idx / DPITCH;
    int m   = rm % AROWS;
    int k   = rm / AROWS;
    asq[idx] = (m < N_ && col < N_) ? f2b(msq[((size_t)k*N_ + m)*N_ + col]) : 0;
}

// ---------------------------------------------------------------------------
// Weight transpose: W[KC][Nout] fp32 -> Wt[Nout][KCpad] bf16 (k zero-padded)
// ---------------------------------------------------------------------------
__global__ __launch_bounds__(256) void wtrans(const float* __restrict__ W, u16* __restrict__ Wt,
                                              int KC, int Nout, int KCpad){
    int k0 = blockIdx.x*64, c0 = blockIdx.y*64;
    int tid = threadIdx.x;
    __shared__ u16 T[64][72];
    #pragma unroll
    for (int it=0; it<2; ++it){
        int lin = it*256 + tid;
        int kl = lin >> 3, seg = lin & 7;
        int gk = k0 + kl, gc = c0 + seg*8;
        u16 tmp[8];
        #pragma unroll
        for (int e=0;e<8;++e) tmp[e] = (gk < KC) ? f2b(W[(size_t)gk*Nout + gc + e]) : 0;
        *(uint4*)&T[kl][seg*8] = *(const uint4*)tmp;
    }
    __syncthreads();
    #pragma unroll
    for (int it=0; it<2; ++it){
        int lin = it*256 + tid;
        int cl = lin >> 3, seg = lin & 7;
        u16 tmp[8];
        #pragma unroll
        for (int j=0;j<8;++j) tmp[j] = T[seg*8+j][cl];
        *(uint4*)(Wt + (size_t)(c0+cl)*KCpad + k0 + seg*8) = *(const uint4*)tmp;
    }
}

// ---------------------------------------------------------------------------
// xfill: Ft0 rows 0..1 (x-part) from src slice (or zeros if x==nullptr)
// ---------------------------------------------------------------------------
__global__ void xfill(const float* __restrict__ x, long xbs, u16* __restrict__ Ft0){
    int idx = blockIdx.x*256 + threadIdx.x;
    if (idx >= B_*N_*2) return;
    int c  = idx & 1;
    int bn = idx >> 1;
    int b  = bn / N_;
    int n  = bn % N_;
    float v = x ? x[(size_t)b*xbs + (size_t)n*2 + c] : 0.f;
    Ft0[((size_t)b*CPAD0 + c)*DPITCH + n] = f2b(v);
}

// ---------------------------------------------------------------------------
// MFMA diffusion, async staging + swizzle. Also (designated blocks k==0,y==0)
// transposes its Bs tiles into F slot0 cols [coff, coff+Cspan) — this is how
// slot0 gets materialized (d1: [x|h] gate version; d2: r*h overwrite).
//   F[bl, m, (k+1)C + coff + c] = sum_n Sk[m,n] * Ft[b0+bl, coff+c, n]
// ---------------------------------------------------------------------------
__global__ __launch_bounds__(256) void diffuse_mfma(u16* __restrict__ F,
                                                    const u16* __restrict__ Ft,
                                                    const u16* __restrict__ asq,
                                                    int C, int KC, int Cpad, int coff,
                                                    int b0){
    int zi = blockIdx.z;
    int k  = zi & 3, bl = zi >> 2;
    const u16* A    = asq + (size_t)k*AROWS*DPITCH;
    const u16* Bt_g = Ft + ((size_t)(b0+bl)*Cpad + coff)*DPITCH;
    u16*       Cm   = F + (size_t)bl*N_*KC + (size_t)(k+1)*C + coff;
    u16*       Fs0  = F + (size_t)bl*N_*KC + coff;   // slot0 target (designated)

    int m0 = blockIdx.y * 128;
    int c0 = blockIdx.x * 64;
    int tid = threadIdx.x;
    int wv = tid >> 6, lane = tid & 63, l15 = lane & 15, quad = lane >> 4;
    int lr = lane >> 3, ls = lane & 7;
    bool desig = (k == 0) && (blockIdx.y == 0);

    __shared__ u16 As[128*64];
    __shared__ u16 Bs[64*64];

    f32x4 acc[2][4];
    #pragma unroll
    for (int i=0;i<2;++i)
        #pragma unroll
        for (int j=0;j<4;++j) acc[i][j] = (f32x4){0.f,0.f,0.f,0.f};

    for (int k0 = 0; k0 < N_; k0 += 64){
        #pragma unroll
        for (int j=0;j<4;++j){
            int row = wv*32 + j*8 + lr;
            int seg = ls ^ lr;
            gl_lds16(A + (size_t)(m0+row)*DPITCH + k0 + seg*8, &As[(wv*32 + j*8)*64]);
        }
        #pragma unroll
        for (int j=0;j<2;++j){
            int row = wv*16 + j*8 + lr;
            int seg = ls ^ lr;
            gl_lds16(Bt_g + (size_t)(c0+row)*DPITCH + k0 + seg*8, &Bs[(wv*16 + j*8)*64]);
        }
        __syncthreads();
        #pragma unroll
        for (int ks = 0; ks < 64; ks += 32){
            int sw = (((ks>>3) + quad) ^ (l15 & 7)) << 3;
            short8 a0 = *(const short8*)&As[(wv*32      + l15)*64 + sw];
            short8 a1 = *(const short8*)&As[(wv*32 + 16 + l15)*64 + sw];
            short8 b0 = *(const short8*)&Bs[(     l15)*64 + sw];
            short8 b1 = *(const short8*)&Bs[(16 + l15)*64 + sw];
            short8 b2 = *(const short8*)&Bs[(32 + l15)*64 + sw];
            short8 b3 = *(const short8*)&Bs[(48 + l15)*64 + sw];
            acc[0][0] = __builtin_amdgcn_mfma_f32_16x16x32_bf16(a0,b0,acc[0][0],0,0,0);
            acc[0][1] = __builtin_amdgcn_mfma_f32_16x16x32_bf16(a0,b1,acc[0][1],0,0,0);
            acc[0][2] = __builtin_amdgcn_mfma_f32_16x16x32_bf16(a0,b2,acc[0][2],0,0,0);
            acc[0][3] = __builtin_amdgcn_mfma_f32_16x16x32_bf16(a0,b3,acc[0][3],0,0,0);
            acc[1][0] = __builtin_amdgcn_mfma_f32_16x16x32_bf16(a1,b0,acc[1][0],0,0,0);
            acc[1][1] = __builtin_amdgcn_mfma_f32_16x16x32_bf16(a1,b1,acc[1][1],0,0,0);
            acc[1][2] = __builtin_amdgcn_mfma_f32_16x16x32_bf16(a1,b2,acc[1][2],0,0,0);
            acc[1][3] = __builtin_amdgcn_mfma_f32_16x16x32_bf16(a1,b3,acc[1][3],0,0,0);
        }
        // designated: transpose Bs back into F slot0 (values bit-identical to Ft)
        if (desig){
            int nl = tid & 63, cg = tid >> 6;
            int n = k0 + nl;
            if (n < N_){
                u16* dst = Fs0 + (size_t)n*KC + c0;
                #pragma unroll
                for (int j=0;j<16;++j){
                    int cl = cg*16 + j;
                    if (coff + c0 + cl < C){
                        int off = cl*64 + (((nl>>3) ^ (cl&7))<<3) + (nl&7);
                        dst[cl] = Bs[off];
                    }
                }
            }
        }
        __syncthreads();
    }
    #pragma unroll
    for (int i=0;i<2;++i){
        #pragma unroll
        for (int j=0;j<4;++j){
            int c = c0 + j*16 + l15;
            #pragma unroll
            for (int r=0;r<4;++r){
                int m = m0 + wv*32 + i*16 + quad*4 + r;
                if (m < N_ && coff + c < C) Cm[(size_t)m*KC + c] = f2b(acc[i][j][r]);
            }
        }
    }
}

// ---------------------------------------------------------------------------
// MFMA GEMM + fused epilogue, async staging + swizzle.
// MODE 0 (Nout=256): c<128 -> zr = sigmoid; c>=128 -> Ft h-rows = r*h_old.
// MODE 1 (Nout=128): h_new = z*h+(1-z)*tanh; writes h, Ft_self, optional Ft2.
// ---------------------------------------------------------------------------
template<int MODE>
__global__ __launch_bounds__(256) void gemm_mfma(const u16* __restrict__ Fb, int KC,
                                                 int rows,
                                                 const u16* __restrict__ Wt, int KCpad,
                                                 const float* __restrict__ bias,
                                                 float* __restrict__ zr,
                                                 float* __restrict__ hb,
                                                 u16* __restrict__ Ft, int Cpad, int Din,
                                                 int b0,
                                                 u16* __restrict__ Ft2){
    int r0 = blockIdx.y * 128;
    int c0 = blockIdx.x * 64;
    int tid = threadIdx.x;
    int wv = tid >> 6, lane = tid & 63, l15 = lane & 15, quad = lane >> 4;
    int lr = lane >> 3, ls = lane & 7;

    __shared__ u16 As[128*64];
    __shared__ u16 Bs[64*64];

    f32x4 acc[2][4];
    #pragma unroll
    for (int i=0;i<2;++i)
        #pragma unroll
        for (int j=0;j<4;++j) acc[i][j] = (f32x4){0.f,0.f,0.f,0.f};

    for (int k0 = 0; k0 < KCpad; k0 += 64){
        if (k0 + 64 <= KC){
            #pragma unroll
            for (int j=0;j<4;++j){
                int row = wv*32 + j*8 + lr;
                int seg = ls ^ lr;
                gl_lds16(Fb + (size_t)(r0+row)*KC + k0 + seg*8, &As[(wv*32 + j*8)*64]);
            }
        } else {
            #pragma unroll
            for (int it=0; it<4; ++it){
                int lin = it*256 + tid;
                int row = lin >> 3, sp = lin & 7;
                int seg = sp ^ (row & 7);
                int gr = r0 + row, gk = k0 + seg*8;
                u16 tmp[8];
                #pragma unroll
                for (int e=0;e<8;++e)
                    tmp[e] = (gk+e < KC) ? Fb[(size_t)gr*KC + gk+e] : (u16)0;
                *(uint4*)&As[row*64 + sp*8] = *(const uint4*)tmp;
            }
        }
        #pragma unroll
        for (int j=0;j<2;++j){
            int row = wv*16 + j*8 + lr;
            int seg = ls ^ lr;
            gl_lds16(Wt + (size_t)(c0+row)*KCpad + k0 + seg*8, &Bs[(wv*16 + j*8)*64]);
        }
        __syncthreads();
        #pragma unroll
        for (int ks = 0; ks < 64; ks += 32){
            int sw = (((ks>>3) + quad) ^ (l15 & 7)) << 3;
            short8 a0 = *(const short8*)&As[(wv*32      + l15)*64 + sw];
            short8 a1 = *(const short8*)&As[(wv*32 + 16 + l15)*64 + sw];
            short8 b0 = *(const short8*)&Bs[(     l15)*64 + sw];
            short8 b1 = *(const short8*)&Bs[(16 + l15)*64 + sw];
            short8 b2 = *(const short8*)&Bs[(32 + l15)*64 + sw];
            short8 b3 = *(const short8*)&Bs[(48 + l15)*64 + sw];
            acc[0][0] = __builtin_amdgcn_mfma_f32_16x16x32_bf16(a0,b0,acc[0][0],0,0,0);
            acc[0][1] = __builtin_amdgcn_mfma_f32_16x16x32_bf16(a0,b1,acc[0][1],0,0,0);
            acc[0][2] = __builtin_amdgcn_mfma_f32_16x16x32_bf16(a0,b2,acc[0][2],0,0,0);
            acc[0][3] = __builtin_amdgcn_mfma_f32_16x16x32_bf16(a0,b3,acc[0][3],0,0,0);
            acc[1][0] = __builtin_amdgcn_mfma_f32_16x16x32_bf16(a1,b0,acc[1][0],0,0,0);
            acc[1][1] = __builtin_amdgcn_mfma_f32_16x16x32_bf16(a1,b1,acc[1][1],0,0,0);
            acc[1][2] = __builtin_amdgcn_mfma_f32_16x16x32_bf16(a1,b2,acc[1][2],0,0,0);
            acc[1][3] = __builtin_amdgcn_mfma_f32_16x16x32_bf16(a1,b3,acc[1][3],0,0,0);
        }
        __syncthreads();
    }
    #pragma unroll
    for (int i=0;i<2;++i){
        #pragma unroll
        for (int j=0;j<4;++j){
            int c = c0 + j*16 + l15;
            #pragma unroll
            for (int r=0;r<4;++r){
                int gr = r0 + wv*32 + i*16 + quad*4 + r;
                if (gr >= rows) continue;
                float v = acc[i][j][r] + bias[c];
                if (MODE == 0){
                    float s = 1.f/(1.f + __expf(-v));
                    if (c < 128){
                        zr[(size_t)gr*256 + c] = s;            // z
                    } else {
                        float hold = hb[(size_t)gr*128 + (c-128)];
                        int bl = gr / N_;
                        int n  = gr - bl*N_;
                        Ft[((size_t)(b0+bl)*Cpad + Din + (c-128))*DPITCH + n] = f2b(s*hold);
                    }
                } else {
                    float hc   = tanhf(v);
                    float z    = zr[(size_t)gr*256 + c];
                    float hold = hb[(size_t)gr*128 + c];
                    float hn   = z*hold + (1.f - z)*hc;
                    hb[(size_t)gr*128 + c] = hn;
                    u16 h16 = f2b(hn);
                    int bl = gr / N_;
                    int n  = gr - bl*N_;
                    Ft[((size_t)(b0+bl)*Cpad + Din + c)*DPITCH + n] = h16;
                    if (Ft2) Ft2[((size_t)(b0+bl)*CPAD1 + c)*DPITCH + n] = h16;
                }
            }
        }
    }
}

// ---------------------------------------------------------------------------
// Projection: out = h1 @ Wp + bp ; writes fp32 d_out AND Ft0 rows 0,1 (decoder
// feedback, bf16) directly.
// ---------------------------------------------------------------------------
__global__ __launch_bounds__(256) void proj(const float* __restrict__ h1,
                                            const float* __restrict__ Wp,
                                            const float* __restrict__ bp,
                                            u16* __restrict__ Ft0,
                                            float* __restrict__ out, int t){
    int row  = blockIdx.x * 4 + (threadIdx.x >> 6);
    int lane = threadIdx.x & 63;
    float v0 = h1[(size_t)row*128 + lane];
    float v1 = h1[(size_t)row*128 + 64 + lane];
    float w00 = Wp[lane*2+0],      w01 = Wp[lane*2+1];
    float w10 = Wp[(64+lane)*2+0], w11 = Wp[(64+lane)*2+1];
    float a0 = v0*w00 + v1*w10;
    float a1 = v0*w01 + v1*w11;
    #pragma unroll
    for (int off=32; off>0; off>>=1){
        a0 += __shfl_down(a0, off);
        a1 += __shfl_down(a1, off);
    }
    if (lane == 0){
        a0 += bp[0];
        a1 += bp[1];
        int b = row / N_, n = row % N_;
        Ft0[((size_t)b*CPAD0 + 0)*DPITCH + n] = f2b(a0);
        Ft0[((size_t)b*CPAD0 + 1)*DPITCH + n] = f2b(a1);
        size_t o = ((size_t)(b*T_ + t)*N_ + n)*2;
        out[o]   = a0;
        out[o+1] = a1;
    }
}

// ---------------------------------------------------------------------------
extern "C" void kernel_launch(void* const* d_in, const int* in_sizes, int n_in,
                              void* d_out, int out_size, void* d_ws, size_t ws_size,
                              hipStream_t stream){
    float* out = (float*)d_out;

    char* pb = (char*)d_ws;
    auto alloc = [&](size_t bytes)->void*{
        void* r = (void*)pb;
        pb += (bytes + 255) & ~(size_t)255;
        return r;
    };

    int* flag = (int*)alloc(16);
    sniff<<<1, 64, 0, stream>>>(d_in[2], flag);

    // fp32 copies of float inputs (skip targets idx 1) — one fused launch
    float* cw[21];
    const int idxs[20] = {0,2,3,4,5,6,7,8,9,10,11,12,13,14,15,16,17,18,19,20};
    CvtArgs ca;
    int maxn = 0;
    for (int ii = 0; ii < 20; ++ii){
        int i = idxs[ii];
        int n = in_sizes[i];
        cw[i] = (float*)alloc((size_t)n*4);
        ca.src[ii] = d_in[i];
        ca.dst[ii] = cw[i];
        ca.n[ii]   = n;
        if (n > maxn) maxn = n;
    }
    cvt_all<<<dim3((maxn+255)/256, 20), 256, 0, stream>>>(ca, flag);
    const float* src = cw[0];

    float* msq  = (float*)alloc((size_t)4*N_*N_*4);
    float* h0   = (float*)alloc((size_t)BN*H_*4);
    float* h1   = (float*)alloc((size_t)BN*H_*4);
    u16*   asq  = (u16*)alloc((size_t)4*AROWS*DPITCH*2);
    u16*   Ft0  = (u16*)alloc((size_t)B_*CPAD0*DPITCH*2);
    u16*   Ft1  = (u16*)alloc((size_t)B_*CPAD1*DPITCH*2);

    // pre-transposed bf16 weights: Wt[Nout][KCpad]
    const int widx[8]  = {3,5,7,9,11,13,15,17};
    const int wKC[8]   = {650,650,1280,1280,650,650,1280,1280};
    const int wNout[8] = {256,128,256,128,256,128,256,128};
    u16* wt[8];
    for (int i=0;i<8;++i){
        int KCpad = (wKC[i] + 63) & ~63;
        wt[i] = (u16*)alloc((size_t)wNout[i]*KCpad*2);
        wtrans<<<dim3(KCpad/64, wNout[i]/64), 256, 0, stream>>>(cw[widx[i]], wt[i], wKC[i], wNout[i], KCpad);
    }

    // adaptive chunk for F (per-cell scratch) + zr
    size_t fixed = (size_t)(pb - (char*)d_ws);
    size_t perb  = (size_t)N_*1280*2 + (size_t)N_*256*4;
    int Bc = 64;
    while (Bc > 1 && fixed + (1<<20) + (size_t)Bc*perb > ws_size) Bc >>= 1;
    float* zr = (float*)alloc((size_t)Bc*N_*256*4);
    u16*   F  = (u16*)alloc((size_t)Bc*N_*1280*2);
    alloc(1<<19);   // slack: OOB-row DMA reads stay inside the workspace

    {   // supports + squared supports, then bf16 row/col-padded copy
        dim3 g((N_+15)/16, (N_+15)/16, 2), b(16,16);
        support_prep<<<g, b, 0, stream>>>(cw[2], msq);
        int tot = 4*AROWS*DPITCH;
        asq_prep<<<dim3((tot+255)/256), 256, 0, stream>>>(msq, asq);
    }
    // zero initial state: h globals + both Ft buffers (bf16 zero == 0x0000)
    hipMemsetAsync(h0, 0, sizeof(float)*(size_t)BN*H_*2, stream);       // h0 and h1
    hipMemsetAsync(Ft0, 0, (size_t)B_*CPAD0*DPITCH*2, stream);
    hipMemsetAsync(Ft1, 0, (size_t)B_*CPAD1*DPITCH*2, stream);

    auto cell = [&](int layer, float* h,
                    const u16* Wg, const float* bg, const u16* Wc, const float* bc,
                    u16* Fts, int Cpad, u16* Ft2){
        int C      = layer ? 256 : 130;
        int KC     = 5*C;
        int KCpad  = (KC + 63) & ~63;
        int Din    = layer ? 128 : 2;
        int ctiles = (C + 63)/64;
        for (int b0 = 0; b0 < B_; b0 += Bc){
            int rows = Bc*N_;
            int gy   = (rows + 127)/128;
            float* hb = h + (size_t)b0*N_*H_;
            // P1: gate diffusion (+ designated blocks write F slot0 = [x|h])
            diffuse_mfma<<<dim3(ctiles, 3, 4*Bc), 256, 0, stream>>>(F, Fts, asq, C, KC, Cpad, 0, b0);
            // P2: gate GEMM (z -> zr; r -> r*h into Ft h-rows)
            gemm_mfma<0><<<dim3(4, gy), 256, 0, stream>>>(F, KC, rows, Wg, KCpad, bg, zr, hb,
                                                          Fts, Cpad, Din, b0, (u16*)nullptr);
            // P3: candidate diffusion over h-cols (+ designated write slot0 h = r*h)
            diffuse_mfma<<<dim3(2, 3, 4*Bc), 256, 0, stream>>>(F, Fts, asq, C, KC, Cpad, Din, b0);
            // P4: candidate GEMM + GRU update (writes h, Ft_self, optional Ft2)
            gemm_mfma<1><<<dim3(2, gy), 256, 0, stream>>>(F, KC, rows, Wc, KCpad, bc, zr, hb,
                                                          Fts, Cpad, Din, b0, Ft2);
        }
    };

    // ---------------- encoder ----------------
    for (int t = 0; t < T_; ++t){
        xfill<<<dim3((B_*N_*2+255)/256), 256, 0, stream>>>(src + (size_t)t*N_*DIN, (long)T_*N_*DIN, Ft0);
        cell(0, h0, wt[0], cw[4], wt[1], cw[6],  Ft0, CPAD0, Ft1);
        cell(1, h1, wt[2], cw[8], wt[3], cw[10], Ft1, CPAD1, (u16*)nullptr);
    }

    // ---------------- decoder ----------------
    xfill<<<dim3((B_*N_*2+255)/256), 256, 0, stream>>>((const float*)nullptr, 0, Ft0);  // GO = 0
    for (int t = 0; t < T_; ++t){
        cell(0, h0, wt[4], cw[12], wt[5], cw[14], Ft0, CPAD0, Ft1);
        cell(1, h1, wt[6], cw[16], wt[7], cw[18], Ft1, CPAD1, (u16*)nullptr);
        proj<<<dim3(BN/4), 256, 0, stream>>>(h1, cw[19], cw[20], Ft0, out, t);
    }
}

// Round 10
// 7909.389 us; speedup vs baseline: 1.6468x; 1.6468x over previous
//
#include <hip/hip_runtime.h>
#include <hip/hip_bf16.h>

#define B_  64
#define T_  12
#define N_  325
#define DIN 2
#define H_  128
#define BN  (B_*N_)    // 20800
#define DPITCH 384     // padded node pitch (k-extent) for transposed/support buffers
#define AROWS 384      // padded m-rows per support matrix

typedef __hip_bfloat16 bf16;
typedef unsigned short u16;
typedef __attribute__((ext_vector_type(8))) short short8;
typedef __attribute__((ext_vector_type(4))) float f32x4;

__device__ __forceinline__ float b2f(bf16 v){ return __bfloat162float(v); }
__device__ __forceinline__ u16 f2b(float f){
    __hip_bfloat16 h = __float2bfloat16(f);
    return *reinterpret_cast<u16*>(&h);
}

// async global->LDS, 16B per lane; dest = base + lane*16 (wave-uniform base)
__device__ __forceinline__ void gl_lds16(const u16* g, u16* l){
    __builtin_amdgcn_global_load_lds(
        (const __attribute__((address_space(1))) unsigned int*)g,
        (__attribute__((address_space(3))) unsigned int*)l, 16, 0, 0);
}

// ---------------------------------------------------------------------------
// Dtype sniffer + one-shot fp32 conversion of all float inputs
// ---------------------------------------------------------------------------
__global__ void sniff(const void* __restrict__ sup, int* __restrict__ flag){
    if (threadIdx.x == 0 && blockIdx.x == 0){
        float sb = 0.f, sf = 0.f;
        for (int n = 0; n < N_; ++n){
            sb += b2f(((const bf16*)sup)[n]);
            sf += ((const float*)sup)[n];
        }
        float db = fabsf(sb - 1.f), df = fabsf(sf - 1.f);
        *flag = (db < df) ? 1 : 0;
    }
}

struct CvtArgs {
    const void* src[20];
    float*      dst[20];
    int         n[20];
};

__global__ void cvt_all(CvtArgs a, const int* __restrict__ flag){
    int ii = blockIdx.y;
    int i  = blockIdx.x*256 + threadIdx.x;
    int n  = a.n[ii];
    if (i >= n) return;
    if (*flag) a.dst[ii][i] = b2f(((const bf16*)a.src[ii])[i]);
    else       a.dst[ii][i] = ((const float*)a.src[ii])[i];
}

// ---------------------------------------------------------------------------
// msq[0]=S0, msq[1]=S0@S0, msq[2]=S1, msq[3]=S1@S1   (fp32)
// ---------------------------------------------------------------------------
__global__ void support_prep(const float* __restrict__ sup, float* __restrict__ msq){
    int s = blockIdx.z;
    int m = blockIdx.y*16 + threadIdx.y;
    int n = blockIdx.x*16 + threadIdx.x;
    __shared__ float As[16][17], Bs[16][17];
    const float* S = sup + (size_t)s*N_*N_;
    float acc = 0.f;
    for (int j0 = 0; j0 < N_; j0 += 16){
        As[threadIdx.y][threadIdx.x] = (m < N_ && j0+threadIdx.x < N_) ? S[m*N_ + j0+threadIdx.x] : 0.f;
        Bs[threadIdx.y][threadIdx.x] = (j0+threadIdx.y < N_ && n < N_) ? S[(j0+threadIdx.y)*N_ + n] : 0.f;
        __syncthreads();
        #pragma unroll
        for (int jj=0; jj<16; ++jj) acc += As[threadIdx.y][jj]*Bs[jj][threadIdx.x];
        __syncthreads();
    }
    if (m < N_ && n < N_){
        msq[(size_t)(2*s  )*N_*N_ + m*N_ + n] = S[m*N_ + n];
        msq[(size_t)(2*s+1)*N_*N_ + m*N_ + n] = acc;
    }
}

// asq[k][m<384][col<384] = bf16(msq[k][m][col]) zero-padded in rows AND cols
__global__ void asq_prep(const float* __restrict__ msq, u16* __restrict__ asq){
    int idx = blockIdx.x*256 + threadIdx.x;
    int total = 4*AROWS*DPITCH;
    if (idx >= total) return;
    int col = idx % DPITCH;
    int rm  = idx / DPITCH;
    int m   = rm % AROWS;
    int k   = rm / AROWS;
    asq[idx] = (m < N_ && col < N_) ? f2b(msq[((size_t)k*N_ + m)*N_ + col]) : 0;
}

// ---------------------------------------------------------------------------
// Weight transpose: W[KC][Nout] fp32 -> Wt[Nout][KCpad] bf16 (k zero-padded)
// ---------------------------------------------------------------------------
__global__ __launch_bounds__(256) void wtrans(const float* __restrict__ W, u16* __restrict__ Wt,
                                              int KC, int Nout, int KCpad){
    int k0 = blockIdx.x*64, c0 = blockIdx.y*64;
    int tid = threadIdx.x;
    __shared__ u16 T[64][72];
    #pragma unroll
    for (int it=0; it<2; ++it){
        int lin = it*256 + tid;
        int kl = lin >> 3, seg = lin & 7;
        int gk = k0 + kl, gc = c0 + seg*8;
        u16 tmp[8];
        #pragma unroll
        for (int e=0;e<8;++e) tmp[e] = (gk < KC) ? f2b(W[(size_t)gk*Nout + gc + e]) : 0;
        *(uint4*)&T[kl][seg*8] = *(const uint4*)tmp;
    }
    __syncthreads();
    #pragma unroll
    for (int it=0; it<2; ++it){
        int lin = it*256 + tid;
        int cl = lin >> 3, seg = lin & 7;
        u16 tmp[8];
        #pragma unroll
        for (int j=0;j<8;++j) tmp[j] = T[seg*8+j][cl];
        *(uint4*)(Wt + (size_t)(c0+cl)*KCpad + k0 + seg*8) = *(const uint4*)tmp;
    }
}

// ---------------------------------------------------------------------------
// fill_t: build F slot0 = [x|h] (bf16, row-major) AND Ft = transpose (c-major,
// node pitch DPITCH, zero-padded). grid (DPITCH/64, Cpad/64, Bc)
// ---------------------------------------------------------------------------
__global__ __launch_bounds__(256) void fill_t(u16* __restrict__ F, u16* __restrict__ Ft,
                                              int C, int KC, int Cpad, int Din, int b0,
                                              const float* __restrict__ x, long xbs,
                                              const float* __restrict__ h){
    int bl = blockIdx.z;
    int bg = b0 + bl;
    int n0 = blockIdx.x*64, c0 = blockIdx.y*64;
    int tid = threadIdx.x;
    __shared__ u16 T[64][72];
    #pragma unroll
    for (int it=0; it<2; ++it){
        int lin = it*256 + tid;
        int nl = lin >> 3, seg = lin & 7;
        int gn = n0 + nl;
        u16 tmp[8];
        #pragma unroll
        for (int e=0;e<8;++e){
            int c = c0 + seg*8 + e;
            float v = 0.f;
            if (gn < N_ && c < C)
                v = (c < Din) ? x[(size_t)bg*xbs + (size_t)gn*Din + c]
                              : h[((size_t)bg*N_ + gn)*H_ + (c - Din)];
            tmp[e] = f2b(v);
        }
        *(uint4*)&T[nl][seg*8] = *(const uint4*)tmp;
        if (gn < N_){
            int cbase = c0 + seg*8;
            u16* dst = F + ((size_t)bl*N_ + gn)*KC + cbase;
            if (cbase + 7 < C){
                *(uint4*)dst = *(const uint4*)tmp;
            } else {
                #pragma unroll
                for (int e=0;e<8;++e) if (cbase + e < C) dst[e] = tmp[e];
            }
        }
    }
    __syncthreads();
    #pragma unroll
    for (int it=0; it<2; ++it){
        int lin = it*256 + tid;
        int cl = lin >> 3, seg = lin & 7;
        u16 tmp[8];
        #pragma unroll
        for (int j=0;j<8;++j) tmp[j] = T[seg*8+j][cl];
        *(uint4*)(Ft + (size_t)bl*Cpad*DPITCH + (size_t)(c0+cl)*DPITCH + n0 + seg*8)
            = *(const uint4*)tmp;
    }
}

// ---------------------------------------------------------------------------
// rh_fill: F[slot0 h-part] = Ft[h-rows] = bf16(r * h)
// ---------------------------------------------------------------------------
__global__ void rh_fill(u16* __restrict__ F, u16* __restrict__ Ft,
                        int KC, int Cpad, int Din, int b0,
                        const float* __restrict__ zr, const float* __restrict__ h){
    int idx = blockIdx.x*256 + threadIdx.x;
    int j   = idx & 127;
    int bnl = idx >> 7;          // grid sized exactly Bc*N_*128/256
    int bl  = bnl / N_;
    int n   = bnl % N_;
    float r  = zr[(size_t)bnl*256 + 128 + j];
    float hv = h[((size_t)b0*N_ + bnl)*128 + j];
    u16 v = f2b(r * hv);
    F[(size_t)bnl*KC + Din + j] = v;
    Ft[((size_t)bl*Cpad + Din + j)*DPITCH + n] = v;
}

// ---------------------------------------------------------------------------
// MFMA diffusion, 4 supports fused per block (B tile staged once, reused 4x).
//   F[bl, m, (s+1)C + coff + c] = sum_n S_s[m,n] * Ft[bl, coff+c, n]
// Block 64(m) x 64(c), BK=64. grid (ctiles, 6, Bc).
// ---------------------------------------------------------------------------
__global__ __launch_bounds__(256) void diffuse_mfma(u16* __restrict__ F,
                                                    const u16* __restrict__ Ft,
                                                    const u16* __restrict__ asq,
                                                    int C, int KC, int Cpad, int coff){
    int bl = blockIdx.z;
    const u16* Bt_g  = Ft + ((size_t)bl*Cpad + coff)*DPITCH;
    u16*       Fbase = F + (size_t)bl*N_*KC + coff;

    int m0 = blockIdx.y * 64;
    int c0 = blockIdx.x * 64;
    int tid = threadIdx.x;
    int wv = tid >> 6, lane = tid & 63, l15 = lane & 15, quad = lane >> 4;
    int lr = lane >> 3, ls = lane & 7;

    __shared__ u16 As[4][64*64];   // 32 KB (one 64x64 tile per support)
    __shared__ u16 Bs[64*64];      // 8 KB

    f32x4 acc[4][4];
    #pragma unroll
    for (int s=0;s<4;++s)
        #pragma unroll
        for (int j=0;j<4;++j) acc[s][j] = (f32x4){0.f,0.f,0.f,0.f};

    for (int k0 = 0; k0 < N_; k0 += 64){
        // B tile (64 c-rows x 64 k), staged ONCE for all 4 supports
        #pragma unroll
        for (int j=0;j<2;++j){
            int row = wv*16 + j*8 + lr;
            int seg = ls ^ lr;
            gl_lds16(Bt_g + (size_t)(c0+row)*DPITCH + k0 + seg*8, &Bs[(wv*16 + j*8)*64]);
        }
        // A tiles: 64 m-rows x 64 k per support (asq zero-padded both dims)
        #pragma unroll
        for (int s=0;s<4;++s){
            #pragma unroll
            for (int j=0;j<2;++j){
                int row = wv*16 + j*8 + lr;
                int seg = ls ^ lr;
                gl_lds16(asq + ((size_t)s*AROWS + m0 + row)*DPITCH + k0 + seg*8,
                         &As[s][(wv*16 + j*8)*64]);
            }
        }
        __syncthreads();
        #pragma unroll
        for (int ks = 0; ks < 64; ks += 32){
            int sw = (((ks>>3) + quad) ^ (l15 & 7)) << 3;
            short8 b0 = *(const short8*)&Bs[(     l15)*64 + sw];
            short8 b1 = *(const short8*)&Bs[(16 + l15)*64 + sw];
            short8 b2 = *(const short8*)&Bs[(32 + l15)*64 + sw];
            short8 b3 = *(const short8*)&Bs[(48 + l15)*64 + sw];
            #pragma unroll
            for (int s=0;s<4;++s){
                short8 a0 = *(const short8*)&As[s][(wv*16 + l15)*64 + sw];
                acc[s][0] = __builtin_amdgcn_mfma_f32_16x16x32_bf16(a0,b0,acc[s][0],0,0,0);
                acc[s][1] = __builtin_amdgcn_mfma_f32_16x16x32_bf16(a0,b1,acc[s][1],0,0,0);
                acc[s][2] = __builtin_amdgcn_mfma_f32_16x16x32_bf16(a0,b2,acc[s][2],0,0,0);
                acc[s][3] = __builtin_amdgcn_mfma_f32_16x16x32_bf16(a0,b3,acc[s][3],0,0,0);
            }
        }
        __syncthreads();
    }
    #pragma unroll
    for (int s=0;s<4;++s){
        u16* Cm = Fbase + (size_t)(s+1)*C;
        #pragma unroll
        for (int j=0;j<4;++j){
            int c = c0 + j*16 + l15;
            #pragma unroll
            for (int r=0;r<4;++r){
                int m = m0 + wv*16 + quad*4 + r;
                if (m < N_ && coff + c < C) Cm[(size_t)m*KC + c] = f2b(acc[s][j][r]);
            }
        }
    }
}

// ---------------------------------------------------------------------------
// MFMA GEMM + fused epilogue, async staging + swizzle. Tile 128m x 128c
// (A staged once serves 128 output cols -> F traffic halved vs 64c).
// MODE 0: zr = sigmoid(out) (Nout=256, grid.x=2).
// MODE 1: h = z*h + (1-z)*tanh(out) (Nout=128, grid.x=1).
// ---------------------------------------------------------------------------
template<int MODE>
__global__ __launch_bounds__(256) void gemm_mfma(const u16* __restrict__ Fb, int KC,
                                                 int rows,
                                                 const u16* __restrict__ Wt, int KCpad,
                                                 const float* __restrict__ bias,
                                                 float* __restrict__ zr,
                                                 float* __restrict__ hb){
    int r0 = blockIdx.y * 128;
    int c0 = blockIdx.x * 128;
    int tid = threadIdx.x;
    int wv = tid >> 6, lane = tid & 63, l15 = lane & 15, quad = lane >> 4;
    int lr = lane >> 3, ls = lane & 7;

    __shared__ u16 As[128*64];   // 16 KB
    __shared__ u16 Bs[128*64];   // 16 KB

    f32x4 acc[2][8];
    #pragma unroll
    for (int i=0;i<2;++i)
        #pragma unroll
        for (int j=0;j<8;++j) acc[i][j] = (f32x4){0.f,0.f,0.f,0.f};

    for (int k0 = 0; k0 < KCpad; k0 += 64){
        if (k0 + 64 <= KC){
            #pragma unroll
            for (int j=0;j<4;++j){
                int row = wv*32 + j*8 + lr;
                int seg = ls ^ lr;
                gl_lds16(Fb + (size_t)(r0+row)*KC + k0 + seg*8, &As[(wv*32 + j*8)*64]);
            }
        } else {
            // K tail: guarded VGPR staging into the same swizzled layout
            #pragma unroll
            for (int it=0; it<4; ++it){
                int lin = it*256 + tid;
                int row = lin >> 3, sp = lin & 7;
                int seg = sp ^ (row & 7);
                int gr = r0 + row, gk = k0 + seg*8;
                u16 tmp[8];
                #pragma unroll
                for (int e=0;e<8;++e)
                    tmp[e] = (gk+e < KC) ? Fb[(size_t)gr*KC + gk+e] : (u16)0;
                *(uint4*)&As[row*64 + sp*8] = *(const uint4*)tmp;
            }
        }
        #pragma unroll
        for (int j=0;j<4;++j){
            int row = wv*32 + j*8 + lr;
            int seg = ls ^ lr;
            gl_lds16(Wt + (size_t)(c0+row)*KCpad + k0 + seg*8, &Bs[(wv*32 + j*8)*64]);
        }
        __syncthreads();
        #pragma unroll
        for (int ks = 0; ks < 64; ks += 32){
            int sw = (((ks>>3) + quad) ^ (l15 & 7)) << 3;
            short8 a0 = *(const short8*)&As[(wv*32      + l15)*64 + sw];
            short8 a1 = *(const short8*)&As[(wv*32 + 16 + l15)*64 + sw];
            #pragma unroll
            for (int j=0;j<8;++j){
                short8 b = *(const short8*)&Bs[(j*16 + l15)*64 + sw];
                acc[0][j] = __builtin_amdgcn_mfma_f32_16x16x32_bf16(a0,b,acc[0][j],0,0,0);
                acc[1][j] = __builtin_amdgcn_mfma_f32_16x16x32_bf16(a1,b,acc[1][j],0,0,0);
            }
        }
        __syncthreads();
    }
    #pragma unroll
    for (int i=0;i<2;++i){
        #pragma unroll
        for (int j=0;j<8;++j){
            int c = c0 + j*16 + l15;
            #pragma unroll
            for (int r=0;r<4;++r){
                int gr = r0 + wv*32 + i*16 + quad*4 + r;
                if (gr >= rows) continue;
                float v = acc[i][j][r] + bias[c];
                if (MODE == 0){
                    v = 1.f/(1.f + __expf(-v));
                    zr[(size_t)gr*256 + c] = v;
                } else {
                    float hc   = tanhf(v);
                    float z    = zr[(size_t)gr*256 + c];
                    float hold = hb[(size_t)gr*128 + c];
                    hb[(size_t)gr*128 + c] = z*hold + (1.f - z)*hc;
                }
            }
        }
    }
}

// ---------------------------------------------------------------------------
// Projection: out = h1 @ Wp + bp ; fp32 xdec + fp32 d_out
// ---------------------------------------------------------------------------
__global__ __launch_bounds__(256) void proj(const float* __restrict__ h1,
                                            const float* __restrict__ Wp,
                                            const float* __restrict__ bp,
                                            float* __restrict__ xdec,
                                            float* __restrict__ out, int t){
    int row  = blockIdx.x * 4 + (threadIdx.x >> 6);
    int lane = threadIdx.x & 63;
    float v0 = h1[(size_t)row*128 + lane];
    float v1 = h1[(size_t)row*128 + 64 + lane];
    float w00 = Wp[lane*2+0],      w01 = Wp[lane*2+1];
    float w10 = Wp[(64+lane)*2+0], w11 = Wp[(64+lane)*2+1];
    float a0 = v0*w00 + v1*w10;
    float a1 = v0*w01 + v1*w11;
    #pragma unroll
    for (int off=32; off>0; off>>=1){
        a0 += __shfl_down(a0, off);
        a1 += __shfl_down(a1, off);
    }
    if (lane == 0){
        a0 += bp[0];
        a1 += bp[1];
        xdec[(size_t)row*2+0] = a0;
        xdec[(size_t)row*2+1] = a1;
        int b = row / N_, n = row % N_;
        size_t o = ((size_t)(b*T_ + t)*N_ + n)*2;
        out[o]   = a0;
        out[o+1] = a1;
    }
}

// ---------------------------------------------------------------------------
extern "C" void kernel_launch(void* const* d_in, const int* in_sizes, int n_in,
                              void* d_out, int out_size, void* d_ws, size_t ws_size,
                              hipStream_t stream){
    float* out = (float*)d_out;

    char* pb = (char*)d_ws;
    auto alloc = [&](size_t bytes)->void*{
        void* r = (void*)pb;
        pb += (bytes + 255) & ~(size_t)255;
        return r;
    };

    int* flag = (int*)alloc(16);
    sniff<<<1, 64, 0, stream>>>(d_in[2], flag);

    // fp32 copies of float inputs (skip targets idx 1) — one fused launch
    float* cw[21];
    const int idxs[20] = {0,2,3,4,5,6,7,8,9,10,11,12,13,14,15,16,17,18,19,20};
    CvtArgs ca;
    int maxn = 0;
    for (int ii = 0; ii < 20; ++ii){
        int i = idxs[ii];
        int n = in_sizes[i];
        cw[i] = (float*)alloc((size_t)n*4);
        ca.src[ii] = d_in[i];
        ca.dst[ii] = cw[i];
        ca.n[ii]   = n;
        if (n > maxn) maxn = n;
    }
    cvt_all<<<dim3((maxn+255)/256, 20), 256, 0, stream>>>(ca, flag);
    const float* src = cw[0];

    float* msq  = (float*)alloc((size_t)4*N_*N_*4);
    float* h0   = (float*)alloc((size_t)BN*H_*4);
    float* h1   = (float*)alloc((size_t)BN*H_*4);
    float* xdec = (float*)alloc((size_t)BN*DIN*4);
    u16*   asq  = (u16*)alloc((size_t)4*AROWS*DPITCH*2);

    // pre-transposed bf16 weights: Wt[Nout][KCpad]
    const int widx[8]  = {3,5,7,9,11,13,15,17};
    const int wKC[8]   = {650,650,1280,1280,650,650,1280,1280};
    const int wNout[8] = {256,128,256,128,256,128,256,128};
    u16* wt[8];
    for (int i=0;i<8;++i){
        int KCpad = (wKC[i] + 63) & ~63;
        wt[i] = (u16*)alloc((size_t)wNout[i]*KCpad*2);
        wtrans<<<dim3(KCpad/64, wNout[i]/64), 256, 0, stream>>>(cw[widx[i]], wt[i], wKC[i], wNout[i], KCpad);
    }

    // adaptive chunk: F + zr + Ft + slack
    size_t fixed = (size_t)(pb - (char*)d_ws);
    size_t perb  = (size_t)N_*1280*2 + (size_t)N_*256*4 + (size_t)256*DPITCH*2;
    int Bc = 64;
    while (Bc > 1 && fixed + (1<<20) + (size_t)Bc*perb > ws_size) Bc >>= 1;
    float* zr = (float*)alloc((size_t)Bc*N_*256*4);
    u16*   F  = (u16*)alloc((size_t)Bc*N_*1280*2);
    u16*   Ft = (u16*)alloc((size_t)Bc*256*DPITCH*2);
    alloc(1<<19);   // slack: OOB-row DMA reads stay inside the workspace

    {   // supports + squared supports, then bf16 row/col-padded copy
        dim3 g((N_+15)/16, (N_+15)/16, 2), b(16,16);
        support_prep<<<g, b, 0, stream>>>(cw[2], msq);
        int tot = 4*AROWS*DPITCH;
        asq_prep<<<dim3((tot+255)/256), 256, 0, stream>>>(msq, asq);
    }
    hipMemsetAsync(h0, 0, sizeof(float)*(size_t)BN*H_*2, stream);  // h0 and h1

    auto cell = [&](int layer, const float* x, long xbs, float* h,
                    const u16* Wg, const float* bg, const u16* Wc, const float* bc){
        int C      = layer ? 256 : 130;
        int KC     = 5*C;
        int KCpad  = (KC + 63) & ~63;
        int Din    = layer ? 128 : 2;
        int ctiles = (C + 63)/64;     // diffuse1 col tiles (3 | 4)
        int Cpad   = ctiles*64;
        for (int b0 = 0; b0 < B_; b0 += Bc){
            int rows = Bc*N_;
            int gy   = (rows + 127)/128;
            float* hb = h + (size_t)b0*N_*H_;
            // P1: slot0 + transpose
            fill_t<<<dim3(DPITCH/64, Cpad/64, Bc), 256, 0, stream>>>(
                F, Ft, C, KC, Cpad, Din, b0, x, xbs, h);
            // P2: gate diffusion (all C cols, 4 supports fused per block)
            diffuse_mfma<<<dim3(ctiles, 6, Bc), 256, 0, stream>>>(F, Ft, asq, C, KC, Cpad, 0);
            // P3: gate GEMM (128x128 tiles)
            gemm_mfma<0><<<dim3(2, gy), 256, 0, stream>>>(F, KC, rows, Wg, KCpad, bg, zr, (float*)nullptr);
            // P4: r*h into slot0 h-part + Ft h-rows
            rh_fill<<<dim3((rows*H_)/256), 256, 0, stream>>>(F, Ft, KC, Cpad, Din, b0, zr, h);
            // P5: candidate diffusion — only the 128 h-cols (x-cols reused from P2)
            diffuse_mfma<<<dim3(2, 6, Bc), 256, 0, stream>>>(F, Ft, asq, C, KC, Cpad, Din);
            // P6: candidate GEMM + GRU update
            gemm_mfma<1><<<dim3(1, gy), 256, 0, stream>>>(F, KC, rows, Wc, KCpad, bc, zr, hb);
        }
    };

    // ---------------- encoder ----------------
    for (int t = 0; t < T_; ++t){
        cell(0, src + (size_t)t*N_*DIN, (long)T_*N_*DIN, h0, wt[0], cw[4], wt[1], cw[6]);
        cell(1, h0, (long)N_*H_, h1, wt[2], cw[8], wt[3], cw[10]);
    }

    // ---------------- decoder ----------------
    hipMemsetAsync(xdec, 0, sizeof(float)*(size_t)BN*DIN, stream);
    for (int t = 0; t < T_; ++t){
        cell(0, xdec, (long)N_*DIN, h0, wt[4], cw[12], wt[5], cw[14]);
        cell(1, h0, (long)N_*H_, h1, wt[6], cw[16], wt[7], cw[18]);
        proj<<<dim3(BN/4), 256, 0, stream>>>(h1, cw[19], cw[20], xdec, out, t);
    }
}

// Round 11
// 6570.686 us; speedup vs baseline: 1.9823x; 1.2037x over previous
//
#include <hip/hip_runtime.h>
#include <hip/hip_bf16.h>

#define B_  64
#define T_  12
#define N_  325
#define DIN 2
#define H_  128
#define BN  (B_*N_)    // 20800
#define DPITCH 384     // padded node pitch (k-extent) for transposed/support buffers
#define AROWS 384      // padded m-rows per support matrix

typedef __hip_bfloat16 bf16;
typedef unsigned short u16;
typedef __attribute__((ext_vector_type(8))) short short8;
typedef __attribute__((ext_vector_type(4))) float f32x4;

__device__ __forceinline__ float b2f(bf16 v){ return __bfloat162float(v); }
__device__ __forceinline__ u16 f2b(float f){
    __hip_bfloat16 h = __float2bfloat16(f);
    return *reinterpret_cast<u16*>(&h);
}

// async global->LDS, 16B per lane; dest = base + lane*16 (wave-uniform base)
__device__ __forceinline__ void gl_lds16(const u16* g, u16* l){
    __builtin_amdgcn_global_load_lds(
        (const __attribute__((address_space(1))) unsigned int*)g,
        (__attribute__((address_space(3))) unsigned int*)l, 16, 0, 0);
}

// ---------------------------------------------------------------------------
// Dtype sniffer + one-shot fp32 conversion of all float inputs
// ---------------------------------------------------------------------------
__global__ void sniff(const void* __restrict__ sup, int* __restrict__ flag){
    if (threadIdx.x == 0 && blockIdx.x == 0){
        float sb = 0.f, sf = 0.f;
        for (int n = 0; n < N_; ++n){
            sb += b2f(((const bf16*)sup)[n]);
            sf += ((const float*)sup)[n];
        }
        float db = fabsf(sb - 1.f), df = fabsf(sf - 1.f);
        *flag = (db < df) ? 1 : 0;
    }
}

struct CvtArgs {
    const void* src[20];
    float*      dst[20];
    int         n[20];
};

__global__ void cvt_all(CvtArgs a, const int* __restrict__ flag){
    int ii = blockIdx.y;
    int i  = blockIdx.x*256 + threadIdx.x;
    int n  = a.n[ii];
    if (i >= n) return;
    if (*flag) a.dst[ii][i] = b2f(((const bf16*)a.src[ii])[i]);
    else       a.dst[ii][i] = ((const float*)a.src[ii])[i];
}

// ---------------------------------------------------------------------------
// msq[0]=S0, msq[1]=S0@S0, msq[2]=S1, msq[3]=S1@S1   (fp32)
// ---------------------------------------------------------------------------
__global__ void support_prep(const float* __restrict__ sup, float* __restrict__ msq){
    int s = blockIdx.z;
    int m = blockIdx.y*16 + threadIdx.y;
    int n = blockIdx.x*16 + threadIdx.x;
    __shared__ float As[16][17], Bs[16][17];
    const float* S = sup + (size_t)s*N_*N_;
    float acc = 0.f;
    for (int j0 = 0; j0 < N_; j0 += 16){
        As[threadIdx.y][threadIdx.x] = (m < N_ && j0+threadIdx.x < N_) ? S[m*N_ + j0+threadIdx.x] : 0.f;
        Bs[threadIdx.y][threadIdx.x] = (j0+threadIdx.y < N_ && n < N_) ? S[(j0+threadIdx.y)*N_ + n] : 0.f;
        __syncthreads();
        #pragma unroll
        for (int jj=0; jj<16; ++jj) acc += As[threadIdx.y][jj]*Bs[jj][threadIdx.x];
        __syncthreads();
    }
    if (m < N_ && n < N_){
        msq[(size_t)(2*s  )*N_*N_ + m*N_ + n] = S[m*N_ + n];
        msq[(size_t)(2*s+1)*N_*N_ + m*N_ + n] = acc;
    }
}

// asq[k][m<384][col<384] = bf16(msq[k][m][col]) zero-padded in rows AND cols
__global__ void asq_prep(const float* __restrict__ msq, u16* __restrict__ asq){
    int idx = blockIdx.x*256 + threadIdx.x;
    int total = 4*AROWS*DPITCH;
    if (idx >= total) return;
    int col = idx % DPITCH;
    int rm  = idx / DPITCH;
    int m   = rm % AROWS;
    int k   = rm / AROWS;
    asq[idx] = (m < N_ && col < N_) ? f2b(msq[((size_t)k*N_ + m)*N_ + col]) : 0;
}

// ---------------------------------------------------------------------------
// Weight transpose: W[KC][Nout] fp32 -> Wt[Nout][KCpad] bf16 (k zero-padded)
// ---------------------------------------------------------------------------
__global__ __launch_bounds__(256) void wtrans(const float* __restrict__ W, u16* __restrict__ Wt,
                                              int KC, int Nout, int KCpad){
    int k0 = blockIdx.x*64, c0 = blockIdx.y*64;
    int tid = threadIdx.x;
    __shared__ u16 T[64][72];
    #pragma unroll
    for (int it=0; it<2; ++it){
        int lin = it*256 + tid;
        int kl = lin >> 3, seg = lin & 7;
        int gk = k0 + kl, gc = c0 + seg*8;
        u16 tmp[8];
        #pragma unroll
        for (int e=0;e<8;++e) tmp[e] = (gk < KC) ? f2b(W[(size_t)gk*Nout + gc + e]) : 0;
        *(uint4*)&T[kl][seg*8] = *(const uint4*)tmp;
    }
    __syncthreads();
    #pragma unroll
    for (int it=0; it<2; ++it){
        int lin = it*256 + tid;
        int cl = lin >> 3, seg = lin & 7;
        u16 tmp[8];
        #pragma unroll
        for (int j=0;j<8;++j) tmp[j] = T[seg*8+j][cl];
        *(uint4*)(Wt + (size_t)(c0+cl)*KCpad + k0 + seg*8) = *(const uint4*)tmp;
    }
}

// ---------------------------------------------------------------------------
// fill_t: build F slot0 = [x|h] (bf16, row-major) AND Ft = transpose (c-major,
// node pitch DPITCH, zero-padded). grid (DPITCH/64, Cpad/64, Bc)
// ---------------------------------------------------------------------------
__global__ __launch_bounds__(256) void fill_t(u16* __restrict__ F, u16* __restrict__ Ft,
                                              int C, int KC, int Cpad, int Din, int b0,
                                              const float* __restrict__ x, long xbs,
                                              const float* __restrict__ h){
    int bl = blockIdx.z;
    int bg = b0 + bl;
    int n0 = blockIdx.x*64, c0 = blockIdx.y*64;
    int tid = threadIdx.x;
    __shared__ u16 T[64][72];
    #pragma unroll
    for (int it=0; it<2; ++it){
        int lin = it*256 + tid;
        int nl = lin >> 3, seg = lin & 7;
        int gn = n0 + nl;
        u16 tmp[8];
        #pragma unroll
        for (int e=0;e<8;++e){
            int c = c0 + seg*8 + e;
            float v = 0.f;
            if (gn < N_ && c < C)
                v = (c < Din) ? x[(size_t)bg*xbs + (size_t)gn*Din + c]
                              : h[((size_t)bg*N_ + gn)*H_ + (c - Din)];
            tmp[e] = f2b(v);
        }
        *(uint4*)&T[nl][seg*8] = *(const uint4*)tmp;
        if (gn < N_){
            int cbase = c0 + seg*8;
            u16* dst = F + ((size_t)bl*N_ + gn)*KC + cbase;
            if (cbase + 7 < C){
                *(uint4*)dst = *(const uint4*)tmp;
            } else {
                #pragma unroll
                for (int e=0;e<8;++e) if (cbase + e < C) dst[e] = tmp[e];
            }
        }
    }
    __syncthreads();
    #pragma unroll
    for (int it=0; it<2; ++it){
        int lin = it*256 + tid;
        int cl = lin >> 3, seg = lin & 7;
        u16 tmp[8];
        #pragma unroll
        for (int j=0;j<8;++j) tmp[j] = T[seg*8+j][cl];
        *(uint4*)(Ft + (size_t)bl*Cpad*DPITCH + (size_t)(c0+cl)*DPITCH + n0 + seg*8)
            = *(const uint4*)tmp;
    }
}

// ---------------------------------------------------------------------------
// rh_fill: F[slot0 h-part] = Ft[h-rows] = bf16(r * h)
// ---------------------------------------------------------------------------
__global__ void rh_fill(u16* __restrict__ F, u16* __restrict__ Ft,
                        int KC, int Cpad, int Din, int b0,
                        const float* __restrict__ zr, const float* __restrict__ h){
    int idx = blockIdx.x*256 + threadIdx.x;
    int j   = idx & 127;
    int bnl = idx >> 7;          // grid sized exactly Bc*N_*128/256
    int bl  = bnl / N_;
    int n   = bnl % N_;
    float r  = zr[(size_t)bnl*256 + 128 + j];
    float hv = h[((size_t)b0*N_ + bnl)*128 + j];
    u16 v = f2b(r * hv);
    F[(size_t)bnl*KC + Din + j] = v;
    Ft[((size_t)bl*Cpad + Din + j)*DPITCH + n] = v;
}

// ---------------------------------------------------------------------------
// MFMA diffusion, async staging + swizzle (R8 geometry: 128m x 64c per block).
// 1-D grid with XCD-pinned decode: the 12 blocks sharing one (bl, c-tile) B
// tile (3 m-tiles x 4 supports) are spaced 8 apart -> same XCD -> L2 reuse.
//   F[bl, m, (k+1)C + coff + c] = sum_n Sk[m,n] * Ft[bl, coff+c, n]
// ---------------------------------------------------------------------------
__global__ __launch_bounds__(256) void diffuse_mfma(u16* __restrict__ F,
                                                    const u16* __restrict__ Ft,
                                                    const u16* __restrict__ asq,
                                                    int C, int KC, int Cpad, int coff,
                                                    int ctiles, int T){
    int i   = blockIdx.x;
    int xcd = i & 7;
    int m8  = i >> 3;
    int tg  = m8 / 12;
    int s   = m8 % 12;
    int t   = tg * 8 + xcd;
    if (t >= T) return;                 // block-uniform, before any barrier
    int bl = t / ctiles;
    int cb = t % ctiles;
    int y  = s % 3;
    int k  = s / 3;

    const u16* A    = asq + (size_t)k*AROWS*DPITCH;
    const u16* Bt_g = Ft + ((size_t)bl*Cpad + coff)*DPITCH;
    u16*       Cm   = F + (size_t)bl*N_*KC + (size_t)(k+1)*C + coff;

    int m0 = y * 128;
    int c0 = cb * 64;
    int tid = threadIdx.x;
    int wv = tid >> 6, lane = tid & 63, l15 = lane & 15, quad = lane >> 4;
    int lr = lane >> 3, ls = lane & 7;

    __shared__ u16 As[128*64];
    __shared__ u16 Bs[64*64];

    f32x4 acc[2][4];
    #pragma unroll
    for (int i2=0;i2<2;++i2)
        #pragma unroll
        for (int j=0;j<4;++j) acc[i2][j] = (f32x4){0.f,0.f,0.f,0.f};

    for (int k0 = 0; k0 < N_; k0 += 64){
        #pragma unroll
        for (int j=0;j<4;++j){
            int row = wv*32 + j*8 + lr;
            int seg = ls ^ lr;
            gl_lds16(A + (size_t)(m0+row)*DPITCH + k0 + seg*8, &As[(wv*32 + j*8)*64]);
        }
        #pragma unroll
        for (int j=0;j<2;++j){
            int row = wv*16 + j*8 + lr;
            int seg = ls ^ lr;
            gl_lds16(Bt_g + (size_t)(c0+row)*DPITCH + k0 + seg*8, &Bs[(wv*16 + j*8)*64]);
        }
        __syncthreads();
        #pragma unroll
        for (int ks = 0; ks < 64; ks += 32){
            int sw = (((ks>>3) + quad) ^ (l15 & 7)) << 3;
            short8 a0 = *(const short8*)&As[(wv*32      + l15)*64 + sw];
            short8 a1 = *(const short8*)&As[(wv*32 + 16 + l15)*64 + sw];
            short8 b0 = *(const short8*)&Bs[(     l15)*64 + sw];
            short8 b1 = *(const short8*)&Bs[(16 + l15)*64 + sw];
            short8 b2 = *(const short8*)&Bs[(32 + l15)*64 + sw];
            short8 b3 = *(const short8*)&Bs[(48 + l15)*64 + sw];
            acc[0][0] = __builtin_amdgcn_mfma_f32_16x16x32_bf16(a0,b0,acc[0][0],0,0,0);
            acc[0][1] = __builtin_amdgcn_mfma_f32_16x16x32_bf16(a0,b1,acc[0][1],0,0,0);
            acc[0][2] = __builtin_amdgcn_mfma_f32_16x16x32_bf16(a0,b2,acc[0][2],0,0,0);
            acc[0][3] = __builtin_amdgcn_mfma_f32_16x16x32_bf16(a0,b3,acc[0][3],0,0,0);
            acc[1][0] = __builtin_amdgcn_mfma_f32_16x16x32_bf16(a1,b0,acc[1][0],0,0,0);
            acc[1][1] = __builtin_amdgcn_mfma_f32_16x16x32_bf16(a1,b1,acc[1][1],0,0,0);
            acc[1][2] = __builtin_amdgcn_mfma_f32_16x16x32_bf16(a1,b2,acc[1][2],0,0,0);
            acc[1][3] = __builtin_amdgcn_mfma_f32_16x16x32_bf16(a1,b3,acc[1][3],0,0,0);
        }
        __syncthreads();
    }
    #pragma unroll
    for (int i2=0;i2<2;++i2){
        #pragma unroll
        for (int j=0;j<4;++j){
            int c = c0 + j*16 + l15;
            #pragma unroll
            for (int r=0;r<4;++r){
                int m = m0 + wv*32 + i2*16 + quad*4 + r;
                if (m < N_ && coff + c < C) Cm[(size_t)m*KC + c] = f2b(acc[i2][j][r]);
            }
        }
    }
}

// ---------------------------------------------------------------------------
// MFMA GEMM + fused epilogue, async staging + swizzle (R8 geometry: 128m x 64c).
// 1-D grid with XCD-pinned decode: the `ct` c-blocks sharing one r-tile's F
// rows are spaced 8 apart -> same XCD -> A re-reads served by L2.
// MODE 0: zr = sigmoid(out) (Nout=256, ct=4). MODE 1: GRU update (ct=2).
// ---------------------------------------------------------------------------
template<int MODE>
__global__ __launch_bounds__(256) void gemm_mfma(const u16* __restrict__ Fb, int KC,
                                                 int rows,
                                                 const u16* __restrict__ Wt, int KCpad,
                                                 const float* __restrict__ bias,
                                                 float* __restrict__ zr,
                                                 float* __restrict__ hb,
                                                 int gy, int ct){
    int i   = blockIdx.x;
    int xcd = i & 7;
    int q   = i >> 3;
    int cb  = q % ct;
    int rt  = (q / ct) * 8 + xcd;
    if (rt >= gy) return;               // block-uniform, before any barrier
    int r0 = rt * 128;
    int c0 = cb * 64;
    int tid = threadIdx.x;
    int wv = tid >> 6, lane = tid & 63, l15 = lane & 15, quad = lane >> 4;
    int lr = lane >> 3, ls = lane & 7;

    __shared__ u16 As[128*64];
    __shared__ u16 Bs[64*64];

    f32x4 acc[2][4];
    #pragma unroll
    for (int i2=0;i2<2;++i2)
        #pragma unroll
        for (int j=0;j<4;++j) acc[i2][j] = (f32x4){0.f,0.f,0.f,0.f};

    for (int k0 = 0; k0 < KCpad; k0 += 64){
        if (k0 + 64 <= KC){
            #pragma unroll
            for (int j=0;j<4;++j){
                int row = wv*32 + j*8 + lr;
                int seg = ls ^ lr;
                gl_lds16(Fb + (size_t)(r0+row)*KC + k0 + seg*8, &As[(wv*32 + j*8)*64]);
            }
        } else {
            // K tail: guarded VGPR staging into the same swizzled layout
            #pragma unroll
            for (int it=0; it<4; ++it){
                int lin = it*256 + tid;
                int row = lin >> 3, sp = lin & 7;
                int seg = sp ^ (row & 7);
                int gr = r0 + row, gk = k0 + seg*8;
                u16 tmp[8];
                #pragma unroll
                for (int e=0;e<8;++e)
                    tmp[e] = (gk+e < KC) ? Fb[(size_t)gr*KC + gk+e] : (u16)0;
                *(uint4*)&As[row*64 + sp*8] = *(const uint4*)tmp;
            }
        }
        #pragma unroll
        for (int j=0;j<2;++j){
            int row = wv*16 + j*8 + lr;
            int seg = ls ^ lr;
            gl_lds16(Wt + (size_t)(c0+row)*KCpad + k0 + seg*8, &Bs[(wv*16 + j*8)*64]);
        }
        __syncthreads();
        #pragma unroll
        for (int ks = 0; ks < 64; ks += 32){
            int sw = (((ks>>3) + quad) ^ (l15 & 7)) << 3;
            short8 a0 = *(const short8*)&As[(wv*32      + l15)*64 + sw];
            short8 a1 = *(const short8*)&As[(wv*32 + 16 + l15)*64 + sw];
            short8 b0 = *(const short8*)&Bs[(     l15)*64 + sw];
            short8 b1 = *(const short8*)&Bs[(16 + l15)*64 + sw];
            short8 b2 = *(const short8*)&Bs[(32 + l15)*64 + sw];
            short8 b3 = *(const short8*)&Bs[(48 + l15)*64 + sw];
            acc[0][0] = __builtin_amdgcn_mfma_f32_16x16x32_bf16(a0,b0,acc[0][0],0,0,0);
            acc[0][1] = __builtin_amdgcn_mfma_f32_16x16x32_bf16(a0,b1,acc[0][1],0,0,0);
            acc[0][2] = __builtin_amdgcn_mfma_f32_16x16x32_bf16(a0,b2,acc[0][2],0,0,0);
            acc[0][3] = __builtin_amdgcn_mfma_f32_16x16x32_bf16(a0,b3,acc[0][3],0,0,0);
            acc[1][0] = __builtin_amdgcn_mfma_f32_16x16x32_bf16(a1,b0,acc[1][0],0,0,0);
            acc[1][1] = __builtin_amdgcn_mfma_f32_16x16x32_bf16(a1,b1,acc[1][1],0,0,0);
            acc[1][2] = __builtin_amdgcn_mfma_f32_16x16x32_bf16(a1,b2,acc[1][2],0,0,0);
            acc[1][3] = __builtin_amdgcn_mfma_f32_16x16x32_bf16(a1,b3,acc[1][3],0,0,0);
        }
        __syncthreads();
    }
    #pragma unroll
    for (int i2=0;i2<2;++i2){
        #pragma unroll
        for (int j=0;j<4;++j){
            int c = c0 + j*16 + l15;
            #pragma unroll
            for (int r=0;r<4;++r){
                int gr = r0 + wv*32 + i2*16 + quad*4 + r;
                if (gr >= rows) continue;
                float v = acc[i2][j][r] + bias[c];
                if (MODE == 0){
                    v = 1.f/(1.f + __expf(-v));
                    zr[(size_t)gr*256 + c] = v;
                } else {
                    float hc   = tanhf(v);
                    float z    = zr[(size_t)gr*256 + c];
                    float hold = hb[(size_t)gr*128 + c];
                    hb[(size_t)gr*128 + c] = z*hold + (1.f - z)*hc;
                }
            }
        }
    }
}

// ---------------------------------------------------------------------------
// Projection: out = h1 @ Wp + bp ; fp32 xdec + fp32 d_out
// ---------------------------------------------------------------------------
__global__ __launch_bounds__(256) void proj(const float* __restrict__ h1,
                                            const float* __restrict__ Wp,
                                            const float* __restrict__ bp,
                                            float* __restrict__ xdec,
                                            float* __restrict__ out, int t){
    int row  = blockIdx.x * 4 + (threadIdx.x >> 6);
    int lane = threadIdx.x & 63;
    float v0 = h1[(size_t)row*128 + lane];
    float v1 = h1[(size_t)row*128 + 64 + lane];
    float w00 = Wp[lane*2+0],      w01 = Wp[lane*2+1];
    float w10 = Wp[(64+lane)*2+0], w11 = Wp[(64+lane)*2+1];
    float a0 = v0*w00 + v1*w10;
    float a1 = v0*w01 + v1*w11;
    #pragma unroll
    for (int off=32; off>0; off>>=1){
        a0 += __shfl_down(a0, off);
        a1 += __shfl_down(a1, off);
    }
    if (lane == 0){
        a0 += bp[0];
        a1 += bp[1];
        xdec[(size_t)row*2+0] = a0;
        xdec[(size_t)row*2+1] = a1;
        int b = row / N_, n = row % N_;
        size_t o = ((size_t)(b*T_ + t)*N_ + n)*2;
        out[o]   = a0;
        out[o+1] = a1;
    }
}

// ---------------------------------------------------------------------------
extern "C" void kernel_launch(void* const* d_in, const int* in_sizes, int n_in,
                              void* d_out, int out_size, void* d_ws, size_t ws_size,
                              hipStream_t stream){
    float* out = (float*)d_out;

    char* pb = (char*)d_ws;
    auto alloc = [&](size_t bytes)->void*{
        void* r = (void*)pb;
        pb += (bytes + 255) & ~(size_t)255;
        return r;
    };

    int* flag = (int*)alloc(16);
    sniff<<<1, 64, 0, stream>>>(d_in[2], flag);

    // fp32 copies of float inputs (skip targets idx 1) — one fused launch
    float* cw[21];
    const int idxs[20] = {0,2,3,4,5,6,7,8,9,10,11,12,13,14,15,16,17,18,19,20};
    CvtArgs ca;
    int maxn = 0;
    for (int ii = 0; ii < 20; ++ii){
        int i = idxs[ii];
        int n = in_sizes[i];
        cw[i] = (float*)alloc((size_t)n*4);
        ca.src[ii] = d_in[i];
        ca.dst[ii] = cw[i];
        ca.n[ii]   = n;
        if (n > maxn) maxn = n;
    }
    cvt_all<<<dim3((maxn+255)/256, 20), 256, 0, stream>>>(ca, flag);
    const float* src = cw[0];

    float* msq  = (float*)alloc((size_t)4*N_*N_*4);
    float* h0   = (float*)alloc((size_t)BN*H_*4);
    float* h1   = (float*)alloc((size_t)BN*H_*4);
    float* xdec = (float*)alloc((size_t)BN*DIN*4);
    u16*   asq  = (u16*)alloc((size_t)4*AROWS*DPITCH*2);

    // pre-transposed bf16 weights: Wt[Nout][KCpad]
    const int widx[8]  = {3,5,7,9,11,13,15,17};
    const int wKC[8]   = {650,650,1280,1280,650,650,1280,1280};
    const int wNout[8] = {256,128,256,128,256,128,256,128};
    u16* wt[8];
    for (int i=0;i<8;++i){
        int KCpad = (wKC[i] + 63) & ~63;
        wt[i] = (u16*)alloc((size_t)wNout[i]*KCpad*2);
        wtrans<<<dim3(KCpad/64, wNout[i]/64), 256, 0, stream>>>(cw[widx[i]], wt[i], wKC[i], wNout[i], KCpad);
    }

    // adaptive chunk: F + zr + Ft + slack
    size_t fixed = (size_t)(pb - (char*)d_ws);
    size_t perb  = (size_t)N_*1280*2 + (size_t)N_*256*4 + (size_t)256*DPITCH*2;
    int Bc = 64;
    while (Bc > 1 && fixed + (1<<20) + (size_t)Bc*perb > ws_size) Bc >>= 1;
    float* zr = (float*)alloc((size_t)Bc*N_*256*4);
    u16*   F  = (u16*)alloc((size_t)Bc*N_*1280*2);
    u16*   Ft = (u16*)alloc((size_t)Bc*256*DPITCH*2);
    alloc(1<<19);   // slack: OOB-row DMA reads stay inside the workspace

    {   // supports + squared supports, then bf16 row/col-padded copy
        dim3 g((N_+15)/16, (N_+15)/16, 2), b(16,16);
        support_prep<<<g, b, 0, stream>>>(cw[2], msq);
        int tot = 4*AROWS*DPITCH;
        asq_prep<<<dim3((tot+255)/256), 256, 0, stream>>>(msq, asq);
    }
    hipMemsetAsync(h0, 0, sizeof(float)*(size_t)BN*H_*2, stream);  // h0 and h1

    auto cell = [&](int layer, const float* x, long xbs, float* h,
                    const u16* Wg, const float* bg, const u16* Wc, const float* bc){
        int C      = layer ? 256 : 130;
        int KC     = 5*C;
        int KCpad  = (KC + 63) & ~63;
        int Din    = layer ? 128 : 2;
        int ctiles = (C + 63)/64;     // diffuse1 col tiles (3 | 4)
        int Cpad   = ctiles*64;
        for (int b0 = 0; b0 < B_; b0 += Bc){
            int rows = Bc*N_;
            int gy   = (rows + 127)/128;
            float* hb = h + (size_t)b0*N_*H_;
            // XCD-pinned 1-D grid sizes
            int T1 = Bc*ctiles, n1 = 8*12*((T1+7)/8);
            int T2 = Bc*2,      n2 = 8*12*((T2+7)/8);
            int ng0 = 8*((gy+7)/8)*4;
            int ng1 = 8*((gy+7)/8)*2;
            // P1: slot0 + transpose
            fill_t<<<dim3(DPITCH/64, Cpad/64, Bc), 256, 0, stream>>>(
                F, Ft, C, KC, Cpad, Din, b0, x, xbs, h);
            // P2: gate diffusion (all C cols)
            diffuse_mfma<<<dim3(n1), 256, 0, stream>>>(F, Ft, asq, C, KC, Cpad, 0, ctiles, T1);
            // P3: gate GEMM
            gemm_mfma<0><<<dim3(ng0), 256, 0, stream>>>(F, KC, rows, Wg, KCpad, bg, zr, (float*)nullptr, gy, 4);
            // P4: r*h into slot0 h-part + Ft h-rows
            rh_fill<<<dim3((rows*H_)/256), 256, 0, stream>>>(F, Ft, KC, Cpad, Din, b0, zr, h);
            // P5: candidate diffusion — only the 128 h-cols (x-cols reused from P2)
            diffuse_mfma<<<dim3(n2), 256, 0, stream>>>(F, Ft, asq, C, KC, Cpad, Din, 2, T2);
            // P6: candidate GEMM + GRU update
            gemm_mfma<1><<<dim3(ng1), 256, 0, stream>>>(F, KC, rows, Wc, KCpad, bc, zr, hb, gy, 2);
        }
    };

    // ---------------- encoder ----------------
    for (int t = 0; t < T_; ++t){
        cell(0, src + (size_t)t*N_*DIN, (long)T_*N_*DIN, h0, wt[0], cw[4], wt[1], cw[6]);
        cell(1, h0, (long)N_*H_, h1, wt[2], cw[8], wt[3], cw[10]);
    }

    // ---------------- decoder ----------------
    hipMemsetAsync(xdec, 0, sizeof(float)*(size_t)BN*DIN, stream);
    for (int t = 0; t < T_; ++t){
        cell(0, xdec, (long)N_*DIN, h0, wt[4], cw[12], wt[5], cw[14]);
        cell(1, h0, (long)N_*H_, h1, wt[6], cw[16], wt[7], cw[18]);
        proj<<<dim3(BN/4), 256, 0, stream>>>(h1, cw[19], cw[20], xdec, out, t);
    }
}